// Round 1
// baseline (810.370 us; speedup 1.0000x reference)
//
#include <hip/hip_runtime.h>
#include <math.h>

#define NN 100000
#define NE 1600000
#define ET (NE + NN)            // 1,700,000 edges incl. self-loops
#define NEG 0.2f
#define EPSF 1e-16f
#define NBLK ((NN + 255) / 256) // 391 scan blocks

// ---------------- GEMM1: h1 = x @ W1  ([NN,165] x [165,256]) ----------------
// block = 256 threads, tile 32 nodes. tx = col-quad (0..63), ty = node-oct (0..3).
// x tile staged in LDS (pad row to 168 for float4 + alignment); W rows streamed
// coalesced from global (169 KB, L2-resident). 8x4 register micro-tile.
__global__ __launch_bounds__(256) void k_gemm1(const float* __restrict__ x,
                                               const float* __restrict__ W,
                                               float* __restrict__ h1) {
    __shared__ float xs[32 * 168];
    const int n0 = blockIdx.x * 32;
    const int t = threadIdx.x;
    for (int idx = t; idx < 32 * 168; idx += 256) {
        const int i = idx / 168, k = idx - i * 168;
        xs[idx] = (k < 165) ? x[(n0 + i) * 165 + k] : 0.0f;
    }
    __syncthreads();
    const int tx = t & 63, ty = t >> 6;
    float acc[8][4];
#pragma unroll
    for (int j = 0; j < 8; ++j)
#pragma unroll
        for (int c = 0; c < 4; ++c) acc[j][c] = 0.0f;
    const float* wp = W + tx * 4;
    for (int k = 0; k < 164; k += 4) {
        const float4 w0 = *(const float4*)(wp + (k + 0) * 256);
        const float4 w1 = *(const float4*)(wp + (k + 1) * 256);
        const float4 w2 = *(const float4*)(wp + (k + 2) * 256);
        const float4 w3 = *(const float4*)(wp + (k + 3) * 256);
#pragma unroll
        for (int j = 0; j < 8; ++j) {
            const float4 xv = *(const float4*)&xs[(ty * 8 + j) * 168 + k];
            acc[j][0] += xv.x * w0.x; acc[j][1] += xv.x * w0.y; acc[j][2] += xv.x * w0.z; acc[j][3] += xv.x * w0.w;
            acc[j][0] += xv.y * w1.x; acc[j][1] += xv.y * w1.y; acc[j][2] += xv.y * w1.z; acc[j][3] += xv.y * w1.w;
            acc[j][0] += xv.z * w2.x; acc[j][1] += xv.z * w2.y; acc[j][2] += xv.z * w2.z; acc[j][3] += xv.z * w2.w;
            acc[j][0] += xv.w * w3.x; acc[j][1] += xv.w * w3.y; acc[j][2] += xv.w * w3.z; acc[j][3] += xv.w * w3.w;
        }
    }
    { // leftover k = 164
        const float4 w0 = *(const float4*)(wp + 164 * 256);
#pragma unroll
        for (int j = 0; j < 8; ++j) {
            const float xv = xs[(ty * 8 + j) * 168 + 164];
            acc[j][0] += xv * w0.x; acc[j][1] += xv * w0.y; acc[j][2] += xv * w0.z; acc[j][3] += xv * w0.w;
        }
    }
#pragma unroll
    for (int j = 0; j < 8; ++j) {
        float4 o; o.x = acc[j][0]; o.y = acc[j][1]; o.z = acc[j][2]; o.w = acc[j][3];
        *(float4*)&h1[(size_t)(n0 + ty * 8 + j) * 256 + tx * 4] = o;
    }
}

// ---------------- attention scalars layer 1: a_src/a_dst [NN,4] -------------
__global__ __launch_bounds__(256) void k_att1(const float* __restrict__ h1,
                                              const float* __restrict__ att_s,
                                              const float* __restrict__ att_d,
                                              float* __restrict__ a_src,
                                              float* __restrict__ a_dst) {
    const int t = threadIdx.x;
    const int n = blockIdx.x * 4 + (t >> 6);
    const int l = t & 63;
#pragma unroll
    for (int h = 0; h < 4; ++h) {
        const float v = h1[(size_t)n * 256 + h * 64 + l];
        float ps = v * att_s[h * 64 + l];
        float pd = v * att_d[h * 64 + l];
        for (int off = 32; off; off >>= 1) {
            ps += __shfl_down(ps, off);
            pd += __shfl_down(pd, off);
        }
        if (l == 0) { a_src[n * 4 + h] = ps; a_dst[n * 4 + h] = pd; }
    }
}

// ---------------- CSR build --------------------------------------------------
__global__ __launch_bounds__(256) void k_hist(const int* __restrict__ dst, int* __restrict__ deg) {
    const int e = blockIdx.x * 256 + threadIdx.x;
    if (e >= ET) return;
    const int d = (e < NE) ? dst[e] : (e - NE);
    atomicAdd(&deg[d], 1);
}

__global__ __launch_bounds__(256) void k_scan1(const int* __restrict__ deg,
                                               int* __restrict__ excl, int* __restrict__ bsum) {
    __shared__ int sh[256];
    const int t = threadIdx.x;
    const int i = blockIdx.x * 256 + t;
    const int v = (i < NN) ? deg[i] : 0;
    sh[t] = v;
    __syncthreads();
    for (int off = 1; off < 256; off <<= 1) {
        int add = (t >= off) ? sh[t - off] : 0;
        __syncthreads();
        sh[t] += add;
        __syncthreads();
    }
    if (i < NN) excl[i] = sh[t] - v;
    if (t == 255) bsum[blockIdx.x] = sh[255];
}

__global__ __launch_bounds__(512) void k_scan2(int* __restrict__ bsum) {
    __shared__ int sh[512];
    const int t = threadIdx.x;
    const int v = (t < NBLK) ? bsum[t] : 0;
    sh[t] = v;
    __syncthreads();
    for (int off = 1; off < 512; off <<= 1) {
        int add = (t >= off) ? sh[t - off] : 0;
        __syncthreads();
        sh[t] += add;
        __syncthreads();
    }
    if (t < NBLK) bsum[t] = sh[t] - v;
}

__global__ __launch_bounds__(256) void k_scan3(const int* __restrict__ excl, const int* __restrict__ bsum,
                                               int* __restrict__ rowptr, int* __restrict__ cursor) {
    const int i = blockIdx.x * 256 + threadIdx.x;
    if (i < NN) {
        const int r = excl[i] + bsum[blockIdx.x];
        rowptr[i] = r;
        cursor[i] = r;
    }
    if (i == 0) rowptr[NN] = ET;
}

__global__ __launch_bounds__(256) void k_scatter(const int* __restrict__ src, const int* __restrict__ dst,
                                                 int* __restrict__ cursor, int* __restrict__ esrc) {
    const int e = blockIdx.x * 256 + threadIdx.x;
    if (e >= ET) return;
    int s, d;
    if (e < NE) { s = src[e]; d = dst[e]; } else { s = d = e - NE; }
    const int pos = atomicAdd(&cursor[d], 1);
    esrc[pos] = s;
}

// ---------------- layer-1 aggregation (wave per node, online softmax) -------
// lane l handles channels 4l..4l+3 (head = l/16). Epilogue fuses bias+ReLU+
// h2 = relu_out @ W2 and layer-2 attention scalars; relu_out never stored.
__global__ __launch_bounds__(256) void k_l1agg(const float* __restrict__ h1,
                                               const float* __restrict__ a_src,
                                               const float* __restrict__ a_dst,
                                               const int* __restrict__ rowptr,
                                               const int* __restrict__ esrc,
                                               const float* __restrict__ b1,
                                               const float* __restrict__ W2,
                                               const float* __restrict__ att_s2,
                                               const float* __restrict__ att_d2,
                                               float* __restrict__ h2,
                                               float* __restrict__ as2,
                                               float* __restrict__ ad2) {
    const int t = threadIdx.x;
    const int n = blockIdx.x * 4 + (t >> 6);
    const int l = t & 63;
    const int head = l >> 4;
    const int c0 = l * 4;
    const float adst = a_dst[n * 4 + head];
    const int beg = rowptr[n], end = rowptr[n + 1];
    float m = -INFINITY, ssum = 0.0f;
    float ax = 0.0f, ay = 0.0f, az = 0.0f, aw = 0.0f;
    for (int idx = beg; idx < end; ++idx) {
        const int s = esrc[idx];
        const float a = a_src[s * 4 + head] + adst;
        const float e = (a > 0.0f) ? a : NEG * a;
        if (e > m) {
            const float r = __expf(m - e); // m = -inf -> 0
            ssum *= r; ax *= r; ay *= r; az *= r; aw *= r;
            m = e;
        }
        const float p = __expf(e - m);
        ssum += p;
        const float4 hv = *(const float4*)&h1[(size_t)s * 256 + c0];
        ax += p * hv.x; ay += p * hv.y; az += p * hv.z; aw += p * hv.w;
    }
    const float inv = 1.0f / (ssum + EPSF);
    const float v0 = fmaxf(ax * inv + b1[c0 + 0], 0.0f);
    const float v1 = fmaxf(ay * inv + b1[c0 + 1], 0.0f);
    const float v2 = fmaxf(az * inv + b1[c0 + 2], 0.0f);
    const float v3 = fmaxf(aw * inv + b1[c0 + 3], 0.0f);
    // h2[n,:] = relu_out @ W2  (W2: [256,2])
    float p0 = v0 * W2[(c0 + 0) * 2 + 0] + v1 * W2[(c0 + 1) * 2 + 0] +
               v2 * W2[(c0 + 2) * 2 + 0] + v3 * W2[(c0 + 3) * 2 + 0];
    float p1 = v0 * W2[(c0 + 0) * 2 + 1] + v1 * W2[(c0 + 1) * 2 + 1] +
               v2 * W2[(c0 + 2) * 2 + 1] + v3 * W2[(c0 + 3) * 2 + 1];
    for (int off = 32; off; off >>= 1) {
        p0 += __shfl_down(p0, off);
        p1 += __shfl_down(p1, off);
    }
    if (l == 0) {
        h2[n * 2 + 0] = p0;
        h2[n * 2 + 1] = p1;
        as2[n] = p0 * att_s2[0] + p1 * att_s2[1];
        ad2[n] = p0 * att_d2[0] + p1 * att_d2[1];
    }
}

// ---------------- layer-2 aggregation + log_softmax (wave per node) ---------
__global__ __launch_bounds__(256) void k_l2agg(const float* __restrict__ h2,
                                               const float* __restrict__ as2,
                                               const float* __restrict__ ad2,
                                               const int* __restrict__ rowptr,
                                               const int* __restrict__ esrc,
                                               const float* __restrict__ b2,
                                               float* __restrict__ out) {
    const int t = threadIdx.x;
    const int n = blockIdx.x * 4 + (t >> 6);
    const int l = t & 63;
    const float adst = ad2[n];
    const int beg = rowptr[n], end = rowptr[n + 1];
    float m = -INFINITY, ssum = 0.0f, a0 = 0.0f, a1 = 0.0f;
    for (int idx = beg + l; idx < end; idx += 64) {
        const int s = esrc[idx];
        const float a = as2[s] + adst;
        const float e = (a > 0.0f) ? a : NEG * a;
        if (e > m) {
            const float r = __expf(m - e);
            ssum *= r; a0 *= r; a1 *= r;
            m = e;
        }
        const float p = __expf(e - m);
        ssum += p;
        a0 += p * h2[s * 2 + 0];
        a1 += p * h2[s * 2 + 1];
    }
    // cross-lane merge of online-softmax states
    float M = m;
    for (int off = 32; off; off >>= 1) M = fmaxf(M, __shfl_down(M, off));
    M = __shfl(M, 0);
    const float wgt = __expf(m - M); // m=-inf lanes -> 0
    ssum *= wgt; a0 *= wgt; a1 *= wgt;
    for (int off = 32; off; off >>= 1) {
        ssum += __shfl_down(ssum, off);
        a0 += __shfl_down(a0, off);
        a1 += __shfl_down(a1, off);
    }
    if (l == 0) {
        const float inv = 1.0f / (ssum + EPSF);
        const float z0 = a0 * inv + b2[0];
        const float z1 = a1 * inv + b2[1];
        const float mz = fmaxf(z0, z1);
        const float lse = mz + __logf(__expf(z0 - mz) + __expf(z1 - mz));
        out[n * 2 + 0] = z0 - lse;
        out[n * 2 + 1] = z1 - lse;
    }
}

extern "C" void kernel_launch(void* const* d_in, const int* in_sizes, int n_in,
                              void* d_out, int out_size, void* d_ws, size_t ws_size,
                              hipStream_t stream) {
    const float* x    = (const float*)d_in[0];
    const int*   src  = (const int*)d_in[1];
    const int*   dst  = (const int*)d_in[2];
    const float* W1   = (const float*)d_in[3];
    const float* as1w = (const float*)d_in[4];
    const float* ad1w = (const float*)d_in[5];
    const float* b1   = (const float*)d_in[6];
    const float* W2   = (const float*)d_in[7];
    const float* as2w = (const float*)d_in[8];
    const float* ad2w = (const float*)d_in[9];
    const float* b2   = (const float*)d_in[10];
    float* out = (float*)d_out;

    char* w = (char*)d_ws;
    float* h1    = (float*)w; w += (size_t)NN * 256 * 4;   // 102.4 MB
    float* a_src = (float*)w; w += (size_t)NN * 4 * 4;
    float* a_dst = (float*)w; w += (size_t)NN * 4 * 4;
    float* h2    = (float*)w; w += (size_t)NN * 2 * 4;
    float* as2   = (float*)w; w += (size_t)NN * 4;
    float* ad2   = (float*)w; w += (size_t)NN * 4;
    int* deg     = (int*)w;   w += (size_t)NN * 4;
    int* excl    = (int*)w;   w += (size_t)NN * 4;
    int* bsum    = (int*)w;   w += 512 * 4;
    int* rowptr  = (int*)w;   w += (size_t)(NN + 1) * 4;
    int* cursor  = (int*)w;   w += (size_t)NN * 4;
    int* esrc    = (int*)w;   w += (size_t)ET * 4;         // 6.8 MB

    hipMemsetAsync(deg, 0, (size_t)NN * 4, stream);
    k_gemm1<<<NN / 32, 256, 0, stream>>>(x, W1, h1);
    k_att1<<<NN / 4, 256, 0, stream>>>(h1, as1w, ad1w, a_src, a_dst);
    k_hist<<<(ET + 255) / 256, 256, 0, stream>>>(dst, deg);
    k_scan1<<<NBLK, 256, 0, stream>>>(deg, excl, bsum);
    k_scan2<<<1, 512, 0, stream>>>(bsum);
    k_scan3<<<NBLK, 256, 0, stream>>>(excl, bsum, rowptr, cursor);
    k_scatter<<<(ET + 255) / 256, 256, 0, stream>>>(src, dst, cursor, esrc);
    k_l1agg<<<NN / 4, 256, 0, stream>>>(h1, a_src, a_dst, rowptr, esrc, b1, W2, as2w, ad2w, h2, as2, ad2);
    k_l2agg<<<NN / 4, 256, 0, stream>>>(h2, as2, ad2, rowptr, esrc, b2, out);
}